// Round 1
// baseline (363.933 us; speedup 1.0000x reference)
//
#include <hip/hip_runtime.h>

// Fused MHA: qkv = x@Wqkv+b; attn per head; out = vals@Wout+b
// B=4, S=2048, D=1024, H=16, Hd=64. All internal compute bf16 MFMA + fp32 accum.

typedef short bf16x8 __attribute__((ext_vector_type(8)));
typedef float f32x4 __attribute__((ext_vector_type(4)));

#define DIMM 1024
#define NH 16
#define HD 64
#define SEQ 2048
#define NB 4
#define MTOT (NB * SEQ)  // 8192

__device__ __forceinline__ short f2bf(float f) {
  __bf16 h = (__bf16)f;
  return __builtin_bit_cast(short, h);
}

__device__ __forceinline__ void cvt_store16(short* dst, float4 a, float4 b) {
  bf16x8 h;
  h[0] = f2bf(a.x); h[1] = f2bf(a.y); h[2] = f2bf(a.z); h[3] = f2bf(a.w);
  h[4] = f2bf(b.x); h[5] = f2bf(b.y); h[6] = f2bf(b.z); h[7] = f2bf(b.w);
  *(bf16x8*)dst = h;
}

// ---------------- transpose + fp32->bf16: out[n][k] = in[k][n] ----------------
__global__ void k_transpose(const float* __restrict__ in, short* __restrict__ out,
                            int K, int N) {
  __shared__ float tile[32][33];
  const int n0 = blockIdx.x * 32, k0 = blockIdx.y * 32;
  const int tx = threadIdx.x, ty = threadIdx.y;
#pragma unroll
  for (int i = 0; i < 32; i += 8)
    tile[ty + i][tx] = in[(size_t)(k0 + ty + i) * N + n0 + tx];
  __syncthreads();
#pragma unroll
  for (int i = 0; i < 32; i += 8)
    out[(size_t)(n0 + ty + i) * K + k0 + tx] = f2bf(tile[tx][ty + i]);
}

// ---------------- GEMM1: qkv = x @ WqkvT^T + b, scatter to split Q/K/V bf16 ----------------
__global__ __launch_bounds__(256) void k_gemm_qkv(
    const float* __restrict__ A, const short* __restrict__ Bt,
    const float* __restrict__ bias,
    short* __restrict__ qw, short* __restrict__ kw, short* __restrict__ vw) {
  __shared__ alignas(16) short Als[128][40];
  __shared__ alignas(16) short Bls[128][40];
  const int tid = threadIdx.x, lane = tid & 63, wid = tid >> 6;
  const int wr = wid >> 1, wc = wid & 1;
  const int bm = blockIdx.x, bn = blockIdx.y;
  const int srow = tid >> 1, scb = (tid & 1) << 4;
  const int fr = lane & 15, fg = lane >> 4;
  f32x4 acc[4][4] = {};
  const float* Ap = A + (size_t)(bm * 128 + srow) * DIMM + scb;
  const short* Bp = Bt + (size_t)(bn * 128 + srow) * DIMM + scb;
  for (int k0 = 0; k0 < DIMM; k0 += 32) {
    __syncthreads();
    const float4* a4 = (const float4*)(Ap + k0);
    float4 f0 = a4[0], f1 = a4[1], f2 = a4[2], f3 = a4[3];
    cvt_store16(&Als[srow][scb], f0, f1);
    cvt_store16(&Als[srow][scb + 8], f2, f3);
    *(bf16x8*)&Bls[srow][scb] = *(const bf16x8*)(Bp + k0);
    *(bf16x8*)&Bls[srow][scb + 8] = *(const bf16x8*)(Bp + k0 + 8);
    __syncthreads();
    bf16x8 af[4], bfv[4];
#pragma unroll
    for (int i = 0; i < 4; i++) {
      af[i] = *(const bf16x8*)&Als[wr * 64 + i * 16 + fr][fg * 8];
      bfv[i] = *(const bf16x8*)&Bls[wc * 64 + i * 16 + fr][fg * 8];
    }
#pragma unroll
    for (int i = 0; i < 4; i++)
#pragma unroll
      for (int j = 0; j < 4; j++)
        acc[i][j] = __builtin_amdgcn_mfma_f32_16x16x32_bf16(af[i], bfv[j], acc[i][j], 0, 0, 0);
  }
#pragma unroll
  for (int i = 0; i < 4; i++) {
    const int row0 = bm * 128 + wr * 64 + i * 16 + fg * 4;
#pragma unroll
    for (int j = 0; j < 4; j++) {
      const int col = bn * 128 + wc * 64 + j * 16 + fr;
      const int h = col / 192;
      const int rem = col - h * 192;
      const int which = rem >> 6, d = rem & 63;
      short* dst = which == 0 ? qw : (which == 1 ? kw : vw);
      const float bs = bias[col];
#pragma unroll
      for (int r = 0; r < 4; r++) {
        const int rr = row0 + r;
        const int bb = rr >> 11, s = rr & 2047;
        dst[((size_t)((bb * NH + h) * SEQ + s)) * HD + d] = f2bf(acc[i][j][r] + bs);
      }
    }
  }
}

// ---------------- flash attention: per (b,h), 64 Q-rows/block, 64-key tiles ----------------
__global__ __launch_bounds__(256) void k_attn(
    const short* __restrict__ qw, const short* __restrict__ kw,
    const short* __restrict__ vw, short* __restrict__ vals) {
  __shared__ alignas(16) short Kls[64][72];
  __shared__ alignas(16) short Vt[64][72];       // [d][k]
  __shared__ alignas(16) short Pls[4][16][72];   // per-wave P tile [q][k]
  const int tid = threadIdx.x, lane = tid & 63, w = tid >> 6;
  const int fr = lane & 15, fg = lane >> 4;
  const int qt = blockIdx.x, bh = blockIdx.y;
  const short* Qp = qw + (size_t)bh * SEQ * HD;
  const short* Kp = kw + (size_t)bh * SEQ * HD;
  const short* Vp = vw + (size_t)bh * SEQ * HD;

  const int qrow = qt * 64 + w * 16 + fr;
  bf16x8 qf0 = *(const bf16x8*)&Qp[(size_t)qrow * HD + fg * 8];
  bf16x8 qf1 = *(const bf16x8*)&Qp[(size_t)qrow * HD + 32 + fg * 8];

  f32x4 o[4] = {};
  float m[4] = {-__builtin_inff(), -__builtin_inff(), -__builtin_inff(), -__builtin_inff()};
  float ln[4] = {};
  const int srow = tid >> 2, scb = (tid & 3) << 4;  // K staging: 64 rows x 4 col-chunks
  const int vd = lane;                              // V staging: d = lane, k-chunk = wave
  const float sc = 0.125f * 1.44269504f;            // scale * log2(e)

  for (int t = 0; t < SEQ / 64; t++) {
    const int kb = t * 64;
    __syncthreads();
    // K tile: coalesced 16B loads, b128 LDS writes
    *(bf16x8*)&Kls[srow][scb] = *(const bf16x8*)&Kp[(size_t)(kb + srow) * HD + scb];
    *(bf16x8*)&Kls[srow][scb + 8] = *(const bf16x8*)&Kp[(size_t)(kb + srow) * HD + scb + 8];
    // V tile transposed: each wave-instruction reads one full 128B V row (coalesced),
    // writes Vt rows with b128 (8 lanes/4-bank start = conflict-optimal)
    short vv[16];
#pragma unroll
    for (int u = 0; u < 16; u++)
      vv[u] = Vp[(size_t)(kb + w * 16 + u) * HD + vd];
    {
      bf16x8 p0, p1;
#pragma unroll
      for (int u = 0; u < 8; u++) { p0[u] = vv[u]; p1[u] = vv[u + 8]; }
      *(bf16x8*)&Vt[vd][w * 16] = p0;
      *(bf16x8*)&Vt[vd][w * 16 + 8] = p1;
    }
    __syncthreads();

    // S = Q K^T  (raw logits; scale folded into exp2)
    f32x4 s[4] = {};
#pragma unroll
    for (int kt = 0; kt < 4; kt++) {
      bf16x8 kf0 = *(const bf16x8*)&Kls[kt * 16 + fr][fg * 8];
      bf16x8 kf1 = *(const bf16x8*)&Kls[kt * 16 + fr][32 + fg * 8];
      s[kt] = __builtin_amdgcn_mfma_f32_16x16x32_bf16(qf0, kf0, s[kt], 0, 0, 0);
      s[kt] = __builtin_amdgcn_mfma_f32_16x16x32_bf16(qf1, kf1, s[kt], 0, 0, 0);
    }

    // online softmax per q-row (rows q=4*fg+r; keys spread over fr lanes)
#pragma unroll
    for (int r = 0; r < 4; r++) {
      float mx = fmaxf(fmaxf(s[0][r], s[1][r]), fmaxf(s[2][r], s[3][r]));
#pragma unroll
      for (int off = 1; off < 16; off <<= 1) mx = fmaxf(mx, __shfl_xor(mx, off));
      const float mnew = fmaxf(m[r], mx);
      const float alpha = exp2f((m[r] - mnew) * sc);
      float sum = 0.f;
#pragma unroll
      for (int kt = 0; kt < 4; kt++) {
        const float p = exp2f((s[kt][r] - mnew) * sc);
        Pls[w][4 * fg + r][kt * 16 + fr] = f2bf(p);
        sum += p;
      }
#pragma unroll
      for (int off = 1; off < 16; off <<= 1) sum += __shfl_xor(sum, off);
      ln[r] = ln[r] * alpha + sum;
      m[r] = mnew;
      o[0][r] *= alpha; o[1][r] *= alpha; o[2][r] *= alpha; o[3][r] *= alpha;
    }

    // O += P V
#pragma unroll
    for (int c = 0; c < 2; c++) {
      bf16x8 pa = *(const bf16x8*)&Pls[w][fr][c * 32 + fg * 8];
#pragma unroll
      for (int dt = 0; dt < 4; dt++) {
        bf16x8 vf = *(const bf16x8*)&Vt[dt * 16 + fr][c * 32 + fg * 8];
        o[dt] = __builtin_amdgcn_mfma_f32_16x16x32_bf16(pa, vf, o[dt], 0, 0, 0);
      }
    }
  }

  // write vals[b][s][h*64+d] bf16
  const int b = bh >> 4, h = bh & 15;
#pragma unroll
  for (int r = 0; r < 4; r++) {
    const float inv = 1.f / ln[r];
    const int row = qt * 64 + w * 16 + 4 * fg + r;
    const size_t base = ((size_t)(b * SEQ + row)) * DIMM + h * HD;
#pragma unroll
    for (int dt = 0; dt < 4; dt++)
      vals[base + dt * 16 + fr] = f2bf(o[dt][r] * inv);
  }
}

// ---------------- GEMM2: out = vals @ WoutT^T + b (fp32 out) ----------------
__global__ __launch_bounds__(256) void k_gemm_out(
    const short* __restrict__ A, const short* __restrict__ Bt,
    const float* __restrict__ bias, float* __restrict__ out) {
  __shared__ alignas(16) short Als[128][40];
  __shared__ alignas(16) short Bls[128][40];
  const int tid = threadIdx.x, lane = tid & 63, wid = tid >> 6;
  const int wr = wid >> 1, wc = wid & 1;
  const int bm = blockIdx.x, bn = blockIdx.y;
  const int srow = tid >> 1, scb = (tid & 1) << 4;
  const int fr = lane & 15, fg = lane >> 4;
  f32x4 acc[4][4] = {};
  const short* Ap = A + (size_t)(bm * 128 + srow) * DIMM + scb;
  const short* Bp = Bt + (size_t)(bn * 128 + srow) * DIMM + scb;
  for (int k0 = 0; k0 < DIMM; k0 += 32) {
    __syncthreads();
    *(bf16x8*)&Als[srow][scb] = *(const bf16x8*)(Ap + k0);
    *(bf16x8*)&Als[srow][scb + 8] = *(const bf16x8*)(Ap + k0 + 8);
    *(bf16x8*)&Bls[srow][scb] = *(const bf16x8*)(Bp + k0);
    *(bf16x8*)&Bls[srow][scb + 8] = *(const bf16x8*)(Bp + k0 + 8);
    __syncthreads();
    bf16x8 af[4], bfv[4];
#pragma unroll
    for (int i = 0; i < 4; i++) {
      af[i] = *(const bf16x8*)&Als[wr * 64 + i * 16 + fr][fg * 8];
      bfv[i] = *(const bf16x8*)&Bls[wc * 64 + i * 16 + fr][fg * 8];
    }
#pragma unroll
    for (int i = 0; i < 4; i++)
#pragma unroll
      for (int j = 0; j < 4; j++)
        acc[i][j] = __builtin_amdgcn_mfma_f32_16x16x32_bf16(af[i], bfv[j], acc[i][j], 0, 0, 0);
  }
#pragma unroll
  for (int i = 0; i < 4; i++) {
    const int row0 = bm * 128 + wr * 64 + i * 16 + fg * 4;
#pragma unroll
    for (int j = 0; j < 4; j++) {
      const int col = bn * 128 + wc * 64 + j * 16 + fr;
      const float bs = bias[col];
#pragma unroll
      for (int r = 0; r < 4; r++)
        out[(size_t)(row0 + r) * DIMM + col] = acc[i][j][r] + bs;
    }
  }
}

extern "C" void kernel_launch(void* const* d_in, const int* in_sizes, int n_in,
                              void* d_out, int out_size, void* d_ws, size_t ws_size,
                              hipStream_t stream) {
  (void)in_sizes; (void)n_in; (void)out_size;
  const float* x = (const float*)d_in[0];
  const float* Wqkv = (const float*)d_in[1];
  const float* bqkv = (const float*)d_in[2];
  const float* Wout = (const float*)d_in[3];
  const float* bout = (const float*)d_in[4];
  float* out = (float*)d_out;

  char* ws = (char*)d_ws;
  const size_t sz_wq = (size_t)3 * DIMM * DIMM * 2;     // WqkvT bf16 [3072][1024]
  const size_t sz_wo = (size_t)DIMM * DIMM * 2;         // WoutT bf16 [1024][1024]
  const size_t sz_qkv1 = (size_t)MTOT * DIMM * 2;       // one of q/k/v split, 16MB
  const size_t off_wq = 0;
  const size_t off_wo = off_wq + sz_wq;
  const size_t off_q = off_wo + sz_wo;
  const size_t off_k = off_q + sz_qkv1;
  const size_t off_v = off_k + sz_qkv1;
  const size_t off_vals = off_v + sz_qkv1;
  const size_t need = off_vals + sz_qkv1;
  if (ws_size < need) return;  // would corrupt memory otherwise; fails visibly

  short* WqT = (short*)(ws + off_wq);
  short* WoT = (short*)(ws + off_wo);
  short* qws = (short*)(ws + off_q);
  short* kws = (short*)(ws + off_k);
  short* vws = (short*)(ws + off_v);
  short* valsws = (short*)(ws + off_vals);

  k_transpose<<<dim3(3 * DIMM / 32, DIMM / 32), dim3(32, 8), 0, stream>>>(Wqkv, WqT, DIMM, 3 * DIMM);
  k_transpose<<<dim3(DIMM / 32, DIMM / 32), dim3(32, 8), 0, stream>>>(Wout, WoT, DIMM, DIMM);
  k_gemm_qkv<<<dim3(MTOT / 128, 3 * DIMM / 128), 256, 0, stream>>>(x, WqT, bqkv, qws, kws, vws);
  k_attn<<<dim3(SEQ / 64, NB * NH), 256, 0, stream>>>(qws, kws, vws, valsws);
  k_gemm_out<<<dim3(MTOT / 128, DIMM / 128), 256, 0, stream>>>(valsws, WoT, bout, out);
}

// Round 2
// 276.272 us; speedup vs baseline: 1.3173x; 1.3173x over previous
//
#include <hip/hip_runtime.h>

// Fused MHA: qkv = x@Wqkv+b; attn per head; out = vals@Wout+b
// B=4, S=2048, D=1024, H=16, Hd=64. Internal compute bf16 MFMA + fp32 accum.
// Round 2: swapped QK^T -> lane-local softmax, defer-max, deferred sum,
// packed P writes, pre-transposed V, bf16 x.

typedef short bf16x8 __attribute__((ext_vector_type(8)));
typedef short bf16x4 __attribute__((ext_vector_type(4)));
typedef float f32x4 __attribute__((ext_vector_type(4)));

#define DIMM 1024
#define NH 16
#define HD 64
#define SEQ 2048
#define NB 4
#define MTOT (NB * SEQ)  // 8192
#define SCQ 0.18033688f  // 0.125 * log2(e), folded into Q

__device__ __forceinline__ short f2bf(float f) {
  __bf16 h = (__bf16)f;
  return __builtin_bit_cast(short, h);
}

// ---------------- x fp32 -> bf16 ----------------
__global__ __launch_bounds__(256) void k_cvt(const float* __restrict__ in,
                                             short* __restrict__ out, int n8) {
  const int stride = gridDim.x * blockDim.x;
  for (int i = blockIdx.x * blockDim.x + threadIdx.x; i < n8; i += stride) {
    const float4* p = (const float4*)(in + (size_t)i * 8);
    float4 a = p[0], b = p[1];
    bf16x8 h;
    h[0] = f2bf(a.x); h[1] = f2bf(a.y); h[2] = f2bf(a.z); h[3] = f2bf(a.w);
    h[4] = f2bf(b.x); h[5] = f2bf(b.y); h[6] = f2bf(b.z); h[7] = f2bf(b.w);
    *(bf16x8*)(out + (size_t)i * 8) = h;
  }
}

// ---------------- transpose + fp32->bf16: out[n][k] = in[k][n] ----------------
__global__ void k_transpose(const float* __restrict__ in, short* __restrict__ out,
                            int K, int N) {
  __shared__ float tile[32][33];
  const int n0 = blockIdx.x * 32, k0 = blockIdx.y * 32;
  const int tx = threadIdx.x, ty = threadIdx.y;
#pragma unroll
  for (int i = 0; i < 32; i += 8)
    tile[ty + i][tx] = in[(size_t)(k0 + ty + i) * N + n0 + tx];
  __syncthreads();
#pragma unroll
  for (int i = 0; i < 32; i += 8)
    out[(size_t)(n0 + ty + i) * K + k0 + tx] = f2bf(tile[tx][ty + i]);
}

// ---------------- GEMM1: qkv = xb @ WqkvT^T + b; scatter Q(scaled)/K/V^T ----------------
__global__ __launch_bounds__(256) void k_gemm_qkv(
    const short* __restrict__ A, const short* __restrict__ Bt,
    const float* __restrict__ bias,
    short* __restrict__ qw, short* __restrict__ kw, short* __restrict__ vtg) {
  __shared__ alignas(16) short Als[128][40];
  __shared__ alignas(16) short Bls[128][40];
  const int tid = threadIdx.x, lane = tid & 63, wid = tid >> 6;
  const int wr = wid >> 1, wc = wid & 1;
  const int bm = blockIdx.x, bn = blockIdx.y;
  const int srow = tid >> 1, scb = (tid & 1) << 4;
  const int fr = lane & 15, fg = lane >> 4;
  f32x4 acc[4][4] = {};
  const short* Ap = A + (size_t)(bm * 128 + srow) * DIMM + scb;
  const short* Bp = Bt + (size_t)(bn * 128 + srow) * DIMM + scb;
  for (int k0 = 0; k0 < DIMM; k0 += 32) {
    __syncthreads();
    *(bf16x8*)&Als[srow][scb] = *(const bf16x8*)(Ap + k0);
    *(bf16x8*)&Als[srow][scb + 8] = *(const bf16x8*)(Ap + k0 + 8);
    *(bf16x8*)&Bls[srow][scb] = *(const bf16x8*)(Bp + k0);
    *(bf16x8*)&Bls[srow][scb + 8] = *(const bf16x8*)(Bp + k0 + 8);
    __syncthreads();
    bf16x8 af[4], bfv[4];
#pragma unroll
    for (int i = 0; i < 4; i++) {
      af[i] = *(const bf16x8*)&Als[wr * 64 + i * 16 + fr][fg * 8];
      bfv[i] = *(const bf16x8*)&Bls[wc * 64 + i * 16 + fr][fg * 8];
    }
#pragma unroll
    for (int i = 0; i < 4; i++)
#pragma unroll
      for (int j = 0; j < 4; j++)
        acc[i][j] = __builtin_amdgcn_mfma_f32_16x16x32_bf16(af[i], bfv[j], acc[i][j], 0, 0, 0);
  }
#pragma unroll
  for (int i = 0; i < 4; i++) {
    const int row0 = bm * 128 + wr * 64 + i * 16 + fg * 4;
    const int bb = row0 >> 11, s0 = row0 & 2047;
#pragma unroll
    for (int j = 0; j < 4; j++) {
      const int col = bn * 128 + wc * 64 + j * 16 + fr;
      const int h = col / 192;
      const int rem = col - h * 192;
      const int which = rem >> 6, d = rem & 63;
      const float bs = bias[col];
      if (which == 2) {
        // V transposed: vtg[bh][d][s], 4 consecutive s -> one 8B store
        bf16x4 pk;
#pragma unroll
        for (int r = 0; r < 4; r++) pk[r] = f2bf(acc[i][j][r] + bs);
        *(bf16x4*)&vtg[((size_t)((bb * NH + h) * HD + d)) * SEQ + s0] = pk;
      } else {
        short* dst = which == 0 ? qw : kw;
        const float scl = which == 0 ? SCQ : 1.f;
#pragma unroll
        for (int r = 0; r < 4; r++)
          dst[((size_t)((bb * NH + h) * SEQ + s0 + r)) * HD + d] =
              f2bf((acc[i][j][r] + bs) * scl);
      }
    }
  }
}

// ---------------- flash attention, swapped-QK lane-local softmax ----------------
// Q pre-scaled by 0.125*log2e, so P = exp2(S - m) directly.
__global__ __launch_bounds__(256) void k_attn(
    const short* __restrict__ qw, const short* __restrict__ kw,
    const short* __restrict__ vt, short* __restrict__ vals) {
  __shared__ alignas(16) short Kls[64][72];      // [key][d]
  __shared__ alignas(16) short Vt[64][72];       // [d][key]
  __shared__ alignas(16) short Pls[4][16][72];   // per-wave [q][key]
  const int tid = threadIdx.x, lane = tid & 63, w = tid >> 6;
  const int fr = lane & 15, fg = lane >> 4;
  const int qt = blockIdx.x, bh = blockIdx.y;
  const short* Qp = qw + (size_t)bh * SEQ * HD;
  const short* Kp = kw + (size_t)bh * SEQ * HD;
  const short* Vtp = vt + (size_t)bh * HD * SEQ;

  const int qrow = qt * 64 + w * 16 + fr;
  const bf16x8 qf0 = *(const bf16x8*)&Qp[(size_t)qrow * HD + fg * 8];
  const bf16x8 qf1 = *(const bf16x8*)&Qp[(size_t)qrow * HD + 32 + fg * 8];

  f32x4 o[4] = {};
  float m = -1e30f;   // running max for q-row = fr (lane-local)
  float ln_p = 0.f;   // per-lane partial sum (this lane's key subset)
  const int srow = tid >> 2, scb = (tid & 3) << 4;

  for (int t = 0; t < SEQ / 64; t++) {
    const int kb = t * 64;
    __syncthreads();
    // K tile [key][d]: 128B rows, 4 threads/row
    *(bf16x8*)&Kls[srow][scb] = *(const bf16x8*)&Kp[(size_t)(kb + srow) * HD + scb];
    *(bf16x8*)&Kls[srow][scb + 8] = *(const bf16x8*)&Kp[(size_t)(kb + srow) * HD + scb + 8];
    // V^T tile [d][key]: rows are d, contiguous in s -> plain vector loads
    *(bf16x8*)&Vt[srow][scb] = *(const bf16x8*)&Vtp[(size_t)srow * SEQ + kb + scb];
    *(bf16x8*)&Vt[srow][scb + 8] = *(const bf16x8*)&Vtp[(size_t)srow * SEQ + kb + scb + 8];
    __syncthreads();

    // S^T = K Q^T : lane holds q = fr, keys kt*16 + fg*4 + r
    f32x4 s4[4];
#pragma unroll
    for (int kt = 0; kt < 4; kt++) {
      const bf16x8 kf0 = *(const bf16x8*)&Kls[kt * 16 + fr][fg * 8];
      const bf16x8 kf1 = *(const bf16x8*)&Kls[kt * 16 + fr][32 + fg * 8];
      f32x4 z = {0.f, 0.f, 0.f, 0.f};
      z = __builtin_amdgcn_mfma_f32_16x16x32_bf16(kf0, qf0, z, 0, 0, 0);
      s4[kt] = __builtin_amdgcn_mfma_f32_16x16x32_bf16(kf1, qf1, z, 0, 0, 0);
    }

    // tile max: in-register tree + cross-fg (2 shuffles)
    float mx = fmaxf(fmaxf(fmaxf(s4[0][0], s4[0][1]), fmaxf(s4[0][2], s4[0][3])),
                     fmaxf(fmaxf(s4[1][0], s4[1][1]), fmaxf(s4[1][2], s4[1][3])));
    mx = fmaxf(mx, fmaxf(fmaxf(fmaxf(s4[2][0], s4[2][1]), fmaxf(s4[2][2], s4[2][3])),
                         fmaxf(fmaxf(s4[3][0], s4[3][1]), fmaxf(s4[3][2], s4[3][3]))));
    mx = fmaxf(mx, __shfl_xor(mx, 16));
    mx = fmaxf(mx, __shfl_xor(mx, 32));

    if (__any(mx > m)) {  // rescale (always tile 0, rare after)
      const float mnew = fmaxf(m, mx);
      const float al = exp2f(m - mnew);
      m = mnew;
      ln_p *= al;
#pragma unroll
      for (int r = 0; r < 4; r++) {
        const float ar = __shfl(al, fg * 4 + r);  // alpha of q-row fg*4+r
        o[0][r] *= ar; o[1][r] *= ar; o[2][r] *= ar; o[3][r] *= ar;
      }
    }

    // P = exp2(S - m), lane-local; pack 4 consecutive keys -> b64 write
    float tsum = 0.f;
#pragma unroll
    for (int kt = 0; kt < 4; kt++) {
      bf16x4 pk;
#pragma unroll
      for (int r = 0; r < 4; r++) {
        const float p = exp2f(s4[kt][r] - m);
        tsum += p;
        pk[r] = f2bf(p);
      }
      *(bf16x4*)&Pls[w][fr][kt * 16 + fg * 4] = pk;
    }
    ln_p += tsum;

    // O += P V
#pragma unroll
    for (int c = 0; c < 2; c++) {
      const bf16x8 pa = *(const bf16x8*)&Pls[w][fr][c * 32 + fg * 8];
#pragma unroll
      for (int dt = 0; dt < 4; dt++) {
        const bf16x8 vf = *(const bf16x8*)&Vt[dt * 16 + fr][c * 32 + fg * 8];
        o[dt] = __builtin_amdgcn_mfma_f32_16x16x32_bf16(pa, vf, o[dt], 0, 0, 0);
      }
    }
  }

  // final denominator: reduce partial sums across the 4 fg lanes of each q
  float lt = ln_p;
  lt += __shfl_xor(lt, 16);
  lt += __shfl_xor(lt, 32);
  const float inv = 1.f / lt;

  const int b = bh >> 4, h = bh & 15;
#pragma unroll
  for (int r = 0; r < 4; r++) {
    const float ir = __shfl(inv, fg * 4 + r);
    const int row = qt * 64 + w * 16 + 4 * fg + r;
    const size_t base = ((size_t)(b * SEQ + row)) * DIMM + h * HD;
#pragma unroll
    for (int dt = 0; dt < 4; dt++)
      vals[base + dt * 16 + fr] = f2bf(o[dt][r] * ir);
  }
}

// ---------------- GEMM2: out = vals @ WoutT^T + b (fp32 out) ----------------
__global__ __launch_bounds__(256) void k_gemm_out(
    const short* __restrict__ A, const short* __restrict__ Bt,
    const float* __restrict__ bias, float* __restrict__ out) {
  __shared__ alignas(16) short Als[128][40];
  __shared__ alignas(16) short Bls[128][40];
  const int tid = threadIdx.x, lane = tid & 63, wid = tid >> 6;
  const int wr = wid >> 1, wc = wid & 1;
  const int bm = blockIdx.x, bn = blockIdx.y;
  const int srow = tid >> 1, scb = (tid & 1) << 4;
  const int fr = lane & 15, fg = lane >> 4;
  f32x4 acc[4][4] = {};
  const short* Ap = A + (size_t)(bm * 128 + srow) * DIMM + scb;
  const short* Bp = Bt + (size_t)(bn * 128 + srow) * DIMM + scb;
  for (int k0 = 0; k0 < DIMM; k0 += 32) {
    __syncthreads();
    *(bf16x8*)&Als[srow][scb] = *(const bf16x8*)(Ap + k0);
    *(bf16x8*)&Als[srow][scb + 8] = *(const bf16x8*)(Ap + k0 + 8);
    *(bf16x8*)&Bls[srow][scb] = *(const bf16x8*)(Bp + k0);
    *(bf16x8*)&Bls[srow][scb + 8] = *(const bf16x8*)(Bp + k0 + 8);
    __syncthreads();
    bf16x8 af[4], bfv[4];
#pragma unroll
    for (int i = 0; i < 4; i++) {
      af[i] = *(const bf16x8*)&Als[wr * 64 + i * 16 + fr][fg * 8];
      bfv[i] = *(const bf16x8*)&Bls[wc * 64 + i * 16 + fr][fg * 8];
    }
#pragma unroll
    for (int i = 0; i < 4; i++)
#pragma unroll
      for (int j = 0; j < 4; j++)
        acc[i][j] = __builtin_amdgcn_mfma_f32_16x16x32_bf16(af[i], bfv[j], acc[i][j], 0, 0, 0);
  }
#pragma unroll
  for (int i = 0; i < 4; i++) {
    const int row0 = bm * 128 + wr * 64 + i * 16 + fg * 4;
#pragma unroll
    for (int j = 0; j < 4; j++) {
      const int col = bn * 128 + wc * 64 + j * 16 + fr;
      const float bs = bias[col];
#pragma unroll
      for (int r = 0; r < 4; r++)
        out[(size_t)(row0 + r) * DIMM + col] = acc[i][j][r] + bs;
    }
  }
}

extern "C" void kernel_launch(void* const* d_in, const int* in_sizes, int n_in,
                              void* d_out, int out_size, void* d_ws, size_t ws_size,
                              hipStream_t stream) {
  (void)in_sizes; (void)n_in; (void)out_size;
  const float* x = (const float*)d_in[0];
  const float* Wqkv = (const float*)d_in[1];
  const float* bqkv = (const float*)d_in[2];
  const float* Wout = (const float*)d_in[3];
  const float* bout = (const float*)d_in[4];
  float* out = (float*)d_out;

  char* ws = (char*)d_ws;
  const size_t sz_wq = (size_t)3 * DIMM * DIMM * 2;   // WqkvT bf16
  const size_t sz_wo = (size_t)DIMM * DIMM * 2;       // WoutT bf16
  const size_t sz_m = (size_t)MTOT * DIMM * 2;        // 16MB slabs
  const size_t off_wq = 0;
  const size_t off_wo = off_wq + sz_wq;
  const size_t off_q = off_wo + sz_wo;
  const size_t off_k = off_q + sz_m;
  const size_t off_vt = off_k + sz_m;
  const size_t off_vals = off_vt + sz_m;  // doubles as xb (attn overwrites after GEMM1)
  const size_t need = off_vals + sz_m;
  if (ws_size < need) return;

  short* WqT = (short*)(ws + off_wq);
  short* WoT = (short*)(ws + off_wo);
  short* qws = (short*)(ws + off_q);
  short* kws = (short*)(ws + off_k);
  short* vtg = (short*)(ws + off_vt);
  short* xb = (short*)(ws + off_vals);    // bf16 x, later reused as vals
  short* valsws = (short*)(ws + off_vals);

  k_cvt<<<2048, 256, 0, stream>>>(x, xb, MTOT * DIMM / 8);
  k_transpose<<<dim3(3 * DIMM / 32, DIMM / 32), dim3(32, 8), 0, stream>>>(Wqkv, WqT, DIMM, 3 * DIMM);
  k_transpose<<<dim3(DIMM / 32, DIMM / 32), dim3(32, 8), 0, stream>>>(Wout, WoT, DIMM, DIMM);
  k_gemm_qkv<<<dim3(MTOT / 128, 3 * DIMM / 128), 256, 0, stream>>>(xb, WqT, bqkv, qws, kws, vtg);
  k_attn<<<dim3(SEQ / 64, NB * NH), 256, 0, stream>>>(qws, kws, vtg, valsws);
  k_gemm_out<<<dim3(MTOT / 128, DIMM / 128), 256, 0, stream>>>(valsws, WoT, bout, out);
}